// Round 7
// baseline (184.797 us; speedup 1.0000x reference)
//
#include <hip/hip_runtime.h>

#define B_ 4
#define C_ 256
#define N_ 4096
#define LOG2E 1.4426950408889634f

typedef short short8 __attribute__((ext_vector_type(8)));
typedef short short4_ __attribute__((ext_vector_type(4)));
typedef float float4v __attribute__((ext_vector_type(4)));
typedef int   int4v  __attribute__((ext_vector_type(4)));
typedef unsigned int uint2v __attribute__((ext_vector_type(2)));
typedef unsigned int u32;

__device__ inline unsigned short f2b(float x){
  unsigned u = __builtin_bit_cast(unsigned, x);
  u = u + 0x7FFFu + ((u >> 16) & 1u);
  return (unsigned short)(u >> 16);
}

__device__ inline u32 cvtpk(float lo, float hi){
  u32 r; asm("v_cvt_pk_bf16_f32 %0, %1, %2" : "=v"(r) : "v"(lo), "v"(hi)); return r;
}

// async global->reg load; result NOT valid until a manual s_waitcnt vmcnt(N)
__device__ inline int4v gld16(const void* p){
  int4v r;
  asm volatile("global_load_dwordx4 %0, %1, off" : "=v"(r) : "v"(p));
  return r;
}

// ---------------- fold BN into weights (log2e folded into Q path) ----------------
__global__ void fold_w_kernel(const float* __restrict__ wq, const float* __restrict__ wk,
    const float* __restrict__ wv,
    const float* gq, const float* bq, const float* mq, const float* vq,
    const float* gk, const float* bk, const float* mk, const float* vk,
    const float* gv, const float* bv, const float* mv, const float* vv,
    unsigned short* wqb, unsigned short* wkb, unsigned short* wvb,
    float* biasq, float* biask, float* biasv){
  int i = blockIdx.x*256 + threadIdx.x;   // 65536 threads
  int o = i >> 8;
  float sv = gv[o]*rsqrtf(vv[o]+1e-5f);
  wvb[i] = f2b(wv[i]*sv);
  if (i < 32*256){
    int oq = i >> 8;
    float sq = gq[oq]*rsqrtf(vq[oq]+1e-5f);
    wqb[i] = f2b(wq[i]*sq*LOG2E);
    float sk = gk[oq]*rsqrtf(vk[oq]+1e-5f);
    wkb[i] = f2b(wk[i]*sk);
  }
  if (i < 256) biasv[i] = bv[i] - mv[i]*(gv[i]*rsqrtf(vv[i]+1e-5f));
  if (i < 32){
    biasq[i] = (bq[i] - mq[i]*(gq[i]*rsqrtf(vq[i]+1e-5f)))*LOG2E;
    biask[i] = bk[i] - mk[i]*(gk[i]*rsqrtf(vk[i]+1e-5f));
  }
}

// ------- merged preprocessing: z=0 upsample+Qconv ; z=1 x2 stage + K/V conv -------
__global__ __launch_bounds__(256, 2)
void pre_kernel(const float* __restrict__ x1, const float* __restrict__ x2,
                const unsigned short* __restrict__ wqb,
                const unsigned short* __restrict__ wkb,
                const unsigned short* __restrict__ wvb,
                const float* __restrict__ biasq, const float* __restrict__ biask,
                const float* __restrict__ biasv,
                float* __restrict__ x1u,
                unsigned short* __restrict__ Qb, unsigned short* __restrict__ Kb,
                unsigned short* __restrict__ Vb){
  __shared__ unsigned short xt[64*260];
  int b = blockIdx.y;
  int t = threadIdx.x;
  int lane = t&63, w = t>>6, l15 = lane&15, g = lane>>4;

  if (blockIdx.z == 0){
    int y = blockIdx.x;
    float fy = 0.5f*y - 0.25f;
    float y0f = floorf(fy); float wy = fy - y0f;
    int y0 = max(0,min(31,(int)y0f)), y1 = max(0,min(31,(int)y0f+1));
    int x = t & 63, cg = t >> 6;
    float fx = 0.5f*x - 0.25f;
    float x0f = floorf(fx); float wx = fx - x0f;
    int x0 = max(0,min(31,(int)x0f)), x1i = max(0,min(31,(int)x0f+1));
    #pragma unroll 8
    for (int i=0;i<64;i++){
      int c = cg + i*4;
      const float* s0 = x1 + ((size_t)(b*C_ + c)*32 + y0)*32;
      const float* s1 = x1 + ((size_t)(b*C_ + c)*32 + y1)*32;
      float v00=s0[x0], v01=s0[x1i], v10=s1[x0], v11=s1[x1i];
      float v0 = v00 + wx*(v01-v00), v1 = v10 + wx*(v11-v10);
      float val = v0 + wy*(v1-v0);
      x1u[(size_t)(b*C_ + c)*N_ + y*64 + x] = val;
      xt[x*260 + c] = f2b(val);
    }
    __syncthreads();
    const unsigned short* arow = xt + (w*16+l15)*260 + g*8;
    short8 a[8];
    #pragma unroll
    for (int kk=0;kk<8;kk++){
      short4_ lo = *(const short4_*)(arow + kk*32);
      short4_ hi = *(const short4_*)(arow + kk*32 + 4);
      short8 af;
      af[0]=lo[0];af[1]=lo[1];af[2]=lo[2];af[3]=lo[3];
      af[4]=hi[0];af[5]=hi[1];af[6]=hi[2];af[7]=hi[3];
      a[kk]=af;
    }
    #pragma unroll
    for (int ot=0; ot<2; ot++){
      int o = ot*16 + l15;
      const unsigned short* wrow = wqb + o*C_ + g*8;
      float4v acc = {0.f,0.f,0.f,0.f};
      #pragma unroll
      for (int kk=0;kk<8;kk++){
        short8 bf = *(const short8*)(wrow + kk*32);
        acc = __builtin_amdgcn_mfma_f32_16x16x32_bf16(a[kk], bf, acc, 0,0,0);
      }
      float bs = biasq[o];
      #pragma unroll
      for (int r=0;r<4;r++){
        float yv = acc[r] + bs;
        yv = yv >= 0.f ? yv : 0.1f*yv;
        int m = y*64 + w*16 + g*4 + r;
        Qb[(size_t)(b*N_+m)*32 + o] = f2b(yv);
      }
    }
  } else {
    int n0 = blockIdx.x*64;
    int n = t & 63, cg = t >> 6;
    #pragma unroll 8
    for (int i=0;i<64;i++){
      int c = cg + i*4;
      float v = x2[(size_t)(b*C_ + c)*N_ + n0 + n];
      xt[n*260 + c] = f2b(v);
    }
    __syncthreads();
    const unsigned short* arow = xt + (w*16+l15)*260 + g*8;
    short8 a[8];
    #pragma unroll
    for (int kk=0;kk<8;kk++){
      short4_ lo = *(const short4_*)(arow + kk*32);
      short4_ hi = *(const short4_*)(arow + kk*32 + 4);
      short8 af;
      af[0]=lo[0];af[1]=lo[1];af[2]=lo[2];af[3]=lo[3];
      af[4]=hi[0];af[5]=hi[1];af[6]=hi[2];af[7]=hi[3];
      a[kk]=af;
    }
    #pragma unroll
    for (int ot=0; ot<2; ot++){
      int o = ot*16 + l15;
      const unsigned short* wrow = wkb + o*C_ + g*8;
      float4v acc = {0.f,0.f,0.f,0.f};
      #pragma unroll
      for (int kk=0;kk<8;kk++){
        short8 bf = *(const short8*)(wrow + kk*32);
        acc = __builtin_amdgcn_mfma_f32_16x16x32_bf16(a[kk], bf, acc, 0,0,0);
      }
      float bs = biask[o];
      #pragma unroll
      for (int r=0;r<4;r++){
        float yv = acc[r] + bs;
        yv = yv >= 0.f ? yv : 0.1f*yv;
        int m = n0 + w*16 + g*4 + r;
        Kb[(size_t)(b*N_+m)*32 + o] = f2b(yv);
      }
    }
    #pragma unroll
    for (int ot=0; ot<16; ot++){
      int o = ot*16 + l15;
      const unsigned short* wrow = wvb + (size_t)o*C_ + g*8;
      float4v acc = {0.f,0.f,0.f,0.f};
      #pragma unroll
      for (int kk=0;kk<8;kk++){
        short8 bf = *(const short8*)(wrow + kk*32);
        acc = __builtin_amdgcn_mfma_f32_16x16x32_bf16(a[kk], bf, acc, 0,0,0);
      }
      float bs = biasv[o];
      #pragma unroll
      for (int r=0;r<4;r++){
        float yv = acc[r] + bs;
        yv = yv >= 0.f ? yv : 0.1f*yv;
        int m = n0 + w*16 + g*4 + r;
        Vb[(size_t)(b*C_ + o)*N_ + m] = f2b(yv);
      }
    }
  }
}

// ---------------- fused flash attention + gamma*out + x1u ----------------
// Grid 256 (XCD-swizzled), 512 threads (8 waves), M=64 per block, full-n sweep.
// Waves 0-3: softmax of 16-row tile w (pipelined 1 tile ahead into P/flags/scl parity bufs).
// All waves: PV split (mh=w>>2: 32 m rows, cq=w&3: 64 c), V in REGISTERS via async
// asm global loads, counted vmcnt. One barrier per iteration.
__global__ __launch_bounds__(512, 2)
void attn_kernel(const unsigned short* __restrict__ Qb,
                 const unsigned short* __restrict__ Kb,
                 const unsigned short* __restrict__ Vb,
                 const float* __restrict__ x1u,
                 const float* __restrict__ gamma_p,
                 float* __restrict__ out){
  // [0,16384): P dbuf (pp*8192 + tile*2048 + row*128 + swz-col)
  // [0,66560): epilogue ow overlay (8 waves * 32 rows * 65 f32)
  // [66560): flags[2][4] ; [66592): scl[2][64] f32 ; [67104): lst[64] f32
  __shared__ __align__(16) char smem[67360];
  int* flagsB = (int*)(smem + 66560);
  float* sclB = (float*)(smem + 66592);
  float* lst  = (float*)(smem + 67104);

  int wg = blockIdx.y*64 + blockIdx.x;
  int id = (wg & 7)*32 + (wg >> 3);           // bijective XCD swizzle (256 = 8*32)
  int b = id >> 6, mblk = id & 63;
  int t = threadIdx.x, lane = t & 63, w = t >> 6;
  int l15 = lane & 15, g = lane >> 4;
  int swz = (l15 & 7) << 4;
  int mh = w >> 2, cq = w & 3;

  short8 qf{};
  if (w < 4)
    qf = *(const short8*)(Qb + (size_t)(b*N_ + mblk*64 + w*16 + l15)*32 + g*8);

  float4v acc[2][4];
  #pragma unroll
  for (int mt=0;mt<2;mt++)
    #pragma unroll
    for (int ct=0;ct<4;ct++) acc[mt][ct] = (float4v){0.f,0.f,0.f,0.f};
  float mrow = -1e30f, lrun = 0.f;
  const float4v zero4 = {0.f,0.f,0.f,0.f};

  const short* vbase = (const short*)Vb + (size_t)(b*C_ + cq*64 + l15)*N_ + g*8;
  const short* kbase = (const short*)Kb + (size_t)(b*N_ + l15)*32 + g*8;

  // QK(tile)+softmax -> P/flags/scl written to parity buffer pdst
  auto softmax_step = [&](const short8 (&kf)[4], int pdst){
    float4v s[4];
    #pragma unroll
    for (int j=0;j<4;j++)
      s[j] = __builtin_amdgcn_mfma_f32_16x16x32_bf16(kf[j], qf, zero4, 0, 0, 0);
    float tmax = fmaxf(fmaxf(fmaxf(s[0][0],s[0][1]),fmaxf(s[0][2],s[0][3])),
               fmaxf(fmaxf(fmaxf(s[1][0],s[1][1]),fmaxf(s[1][2],s[1][3])),
               fmaxf(fmaxf(fmaxf(s[2][0],s[2][1]),fmaxf(s[2][2],s[2][3])),
                     fmaxf(fmaxf(s[3][0],s[3][1]),fmaxf(s[3][2],s[3][3])))));
    int trig = __any((tmax > mrow + 8.f) ? 1 : 0) ? 1 : 0;
    if (lane == 0) flagsB[pdst*4 + w] = trig;
    if (trig){
      float tm = fmaxf(tmax, __shfl_xor(tmax, 16));
      tm = fmaxf(tm, __shfl_xor(tm, 32));
      float mnew = fmaxf(mrow, tm);
      float sc = exp2f(mrow - mnew);
      mrow = mnew; lrun *= sc;
      if (lane < 16) sclB[pdst*64 + w*16 + l15] = sc;
    }
    char* pw = smem + pdst*8192 + w*2048 + l15*128;
    #pragma unroll
    for (int j=0;j<4;j++){
      float p0 = exp2f(s[j][0]-mrow), p1 = exp2f(s[j][1]-mrow);
      float p2 = exp2f(s[j][2]-mrow), p3 = exp2f(s[j][3]-mrow);
      lrun += (p0+p1)+(p2+p3);
      u32 lo = cvtpk(p0, p1);
      u32 hi = cvtpk(p2, p3);
      *(uint2v*)(pw + ((j*32 + g*8) ^ swz)) = (uint2v){lo, hi};
    }
  };

  int4v vA[8], vB[8], kA[4], kB[4];

  // prologue: K(0) sync, softmax(0) -> buf0; issue V(0)->vA, K(1)->kA
  if (w < 4){
    short8 k0[4];
    #pragma unroll
    for (int j=0;j<4;j++) k0[j] = *(const short8*)(kbase + (size_t)(j*16)*32);
    softmax_step(k0, 0);
  }
  #pragma unroll
  for (int ct=0;ct<4;ct++)
    #pragma unroll
    for (int kh=0;kh<2;kh++)
      vA[ct*2+kh] = gld16(vbase + (size_t)ct*16*N_ + kh*32);
  if (w < 4){
    #pragma unroll
    for (int j=0;j<4;j++) kA[j] = gld16(kbase + (size_t)(64 + j*16)*32);
  }
  __syncthreads();

  auto body = [&](int tt, int pp, int4v (&vC)[8], int4v (&vN)[8],
                  int4v (&kC)[4], int4v (&kN)[4]){
    int n1 = (tt+1) & 63, n2 = (tt+2) & 63;
    // issue next-tile V (all waves), K (softmax waves); wrap-around issues are harmless
    #pragma unroll
    for (int ct=0;ct<4;ct++)
      #pragma unroll
      for (int kh=0;kh<2;kh++)
        vN[ct*2+kh] = gld16(vbase + (size_t)ct*16*N_ + n1*64 + kh*32);
    if (w < 4){
      #pragma unroll
      for (int j=0;j<4;j++) kN[j] = gld16(kbase + (size_t)(n2*64 + j*16)*32);
      asm volatile("s_waitcnt vmcnt(12)");
    } else {
      asm volatile("s_waitcnt vmcnt(8)");
    }
    __builtin_amdgcn_sched_barrier(0);
    if (w < 4 && tt < 63){
      short8 kk[4];
      #pragma unroll
      for (int j=0;j<4;j++) kk[j] = __builtin_bit_cast(short8, kC[j]);
      softmax_step(kk, pp ^ 1);
    }
    // rescale + PV(t) from P buf[pp] and V regs
    int f0 = flagsB[pp*4 + mh*2];
    int f1 = flagsB[pp*4 + mh*2 + 1];
    if (f0){
      float4v sv = *(float4v*)(sclB + pp*64 + (mh*2)*16 + g*4);
      #pragma unroll
      for (int ct=0;ct<4;ct++){
        acc[0][ct][0]*=sv[0]; acc[0][ct][1]*=sv[1];
        acc[0][ct][2]*=sv[2]; acc[0][ct][3]*=sv[3];
      }
    }
    if (f1){
      float4v sv = *(float4v*)(sclB + pp*64 + (mh*2+1)*16 + g*4);
      #pragma unroll
      for (int ct=0;ct<4;ct++){
        acc[1][ct][0]*=sv[0]; acc[1][ct][1]*=sv[1];
        acc[1][ct][2]*=sv[2]; acc[1][ct][3]*=sv[3];
      }
    }
    #pragma unroll
    for (int kh=0; kh<2; kh++){
      int ko = (kh*64 + g*16) ^ swz;
      short8 pa0 = *(const short8*)(smem + pp*8192 + (mh*2  )*2048 + l15*128 + ko);
      short8 pa1 = *(const short8*)(smem + pp*8192 + (mh*2+1)*2048 + l15*128 + ko);
      #pragma unroll
      for (int ct=0; ct<4; ct++){
        short8 vf = __builtin_bit_cast(short8, vC[ct*2+kh]);
        acc[0][ct] = __builtin_amdgcn_mfma_f32_16x16x32_bf16(pa0, vf, acc[0][ct], 0, 0, 0);
        acc[1][ct] = __builtin_amdgcn_mfma_f32_16x16x32_bf16(pa1, vf, acc[1][ct], 0, 0, 0);
      }
    }
    __syncthreads();
  };

  for (int tt=0; tt<64; tt+=2){
    body(tt,   0, vA, vB, kA, kB);
    body(tt+1, 1, vB, vA, kB, kA);
  }
  asm volatile("s_waitcnt vmcnt(0)");   // drain wrap-around issues before reg reuse
  __builtin_amdgcn_sched_barrier(0);

  // epilogue: row sums, normalize, LDS transpose (overlay), fused residual store
  if (w < 4){
    lrun += __shfl_xor(lrun, 16);
    lrun += __shfl_xor(lrun, 32);
    if (lane < 16) lst[w*16 + l15] = lrun;
  }
  __syncthreads();
  float4v lv[2];
  #pragma unroll
  for (int mt=0;mt<2;mt++) lv[mt] = *(float4v*)(lst + (mh*2+mt)*16 + g*4);
  float gm = gamma_p[0];
  float* ow = (float*)smem + w*2080;   // 32 rows x 65 stride
  #pragma unroll
  for (int mt=0;mt<2;mt++){
    #pragma unroll
    for (int ct=0;ct<4;ct++){
      #pragma unroll
      for (int r=0;r<4;r++)
        ow[(mt*16 + g*4 + r)*65 + ct*16 + l15] = acc[mt][ct][r] / lv[mt][r];
    }
  }
  __syncthreads();
  int m31 = lane & 31, ch = lane >> 5;
  const float* xr = x1u + (size_t)(b*C_ + cq*64)*N_ + mblk*64 + mh*32;
  float* orow = out + (size_t)(b*C_ + cq*64)*N_ + mblk*64 + mh*32;
  #pragma unroll 8
  for (int i=0; i<32; i++){
    int c_l = i*2 + ch;
    float v = ow[m31*65 + c_l];
    orow[(size_t)c_l*N_ + m31] = gm*v + xr[(size_t)c_l*N_ + m31];
  }
}

extern "C" void kernel_launch(void* const* d_in, const int* in_sizes, int n_in,
                              void* d_out, int out_size, void* d_ws, size_t ws_size,
                              hipStream_t stream){
  (void)in_sizes; (void)n_in; (void)out_size; (void)ws_size;
  const float* x1 = (const float*)d_in[0];
  const float* x2 = (const float*)d_in[1];
  const float* wq = (const float*)d_in[2];
  const float* wk = (const float*)d_in[3];
  const float* wv = (const float*)d_in[4];
  const float* gq = (const float*)d_in[5];
  const float* bq = (const float*)d_in[6];
  const float* mq = (const float*)d_in[7];
  const float* vq = (const float*)d_in[8];
  const float* gk = (const float*)d_in[9];
  const float* bk = (const float*)d_in[10];
  const float* mk = (const float*)d_in[11];
  const float* vk = (const float*)d_in[12];
  const float* gv = (const float*)d_in[13];
  const float* bv = (const float*)d_in[14];
  const float* mv = (const float*)d_in[15];
  const float* vv = (const float*)d_in[16];
  const float* gamma = (const float*)d_in[17];
  float* out = (float*)d_out;

  char* p = (char*)d_ws;
  float* x1u          = (float*)p;          p += (size_t)B_*C_*N_*4;   // 16 MB
  unsigned short* Qb  = (unsigned short*)p; p += (size_t)B_*N_*32*2;   // 1 MB
  unsigned short* Kb  = (unsigned short*)p; p += (size_t)B_*N_*32*2;   // 1 MB
  unsigned short* Vb  = (unsigned short*)p; p += (size_t)B_*C_*N_*2;   // 8 MB
  unsigned short* wqb = (unsigned short*)p; p += 32*256*2;
  unsigned short* wkb = (unsigned short*)p; p += 32*256*2;
  unsigned short* wvb = (unsigned short*)p; p += 256*256*2;
  float* biasq        = (float*)p;          p += 32*4;
  float* biask        = (float*)p;          p += 32*4;
  float* biasv        = (float*)p;          p += 256*4;

  fold_w_kernel<<<256, 256, 0, stream>>>(wq,wk,wv,gq,bq,mq,vq,gk,bk,mk,vk,gv,bv,mv,vv,
                                         wqb,wkb,wvb,biasq,biask,biasv);
  pre_kernel<<<dim3(64,4,2), 256, 0, stream>>>(x1, x2, wqb, wkb, wvb,
                                               biasq, biask, biasv, x1u, Qb, Kb, Vb);
  attn_kernel<<<dim3(64,4), 512, 0, stream>>>(Qb, Kb, Vb, x1u, gamma, out);
}

// Round 8
// 118.222 us; speedup vs baseline: 1.5631x; 1.5631x over previous
//
#include <hip/hip_runtime.h>

#define B_ 4
#define C_ 256
#define N_ 4096
#define LOG2E 1.4426950408889634f

typedef short short8 __attribute__((ext_vector_type(8)));
typedef short short4_ __attribute__((ext_vector_type(4)));
typedef float float4v __attribute__((ext_vector_type(4)));
typedef unsigned int uint2v __attribute__((ext_vector_type(2)));
typedef unsigned int u32;

__device__ inline unsigned short f2b(float x){
  unsigned u = __builtin_bit_cast(unsigned, x);
  u = u + 0x7FFFu + ((u >> 16) & 1u);
  return (unsigned short)(u >> 16);
}

__device__ inline u32 cvtpk(float lo, float hi){
  u32 r; asm("v_cvt_pk_bf16_f32 %0, %1, %2" : "=v"(r) : "v"(lo), "v"(hi)); return r;
}

__device__ inline void gload16(const void* g, void* l){
  __builtin_amdgcn_global_load_lds((const __attribute__((address_space(1))) u32*)g,
                                   (__attribute__((address_space(3))) u32*)l, 16, 0, 0);
}

// ---------------- fold BN into weights (log2e folded into Q path) ----------------
__global__ void fold_w_kernel(const float* __restrict__ wq, const float* __restrict__ wk,
    const float* __restrict__ wv,
    const float* gq, const float* bq, const float* mq, const float* vq,
    const float* gk, const float* bk, const float* mk, const float* vk,
    const float* gv, const float* bv, const float* mv, const float* vv,
    unsigned short* wqb, unsigned short* wkb, unsigned short* wvb,
    float* biasq, float* biask, float* biasv){
  int i = blockIdx.x*256 + threadIdx.x;   // 65536 threads
  int o = i >> 8;
  float sv = gv[o]*rsqrtf(vv[o]+1e-5f);
  wvb[i] = f2b(wv[i]*sv);
  if (i < 32*256){
    int oq = i >> 8;
    float sq = gq[oq]*rsqrtf(vq[oq]+1e-5f);
    wqb[i] = f2b(wq[i]*sq*LOG2E);
    float sk = gk[oq]*rsqrtf(vk[oq]+1e-5f);
    wkb[i] = f2b(wk[i]*sk);
  }
  if (i < 256) biasv[i] = bv[i] - mv[i]*(gv[i]*rsqrtf(vv[i]+1e-5f));
  if (i < 32){
    biasq[i] = (bq[i] - mq[i]*(gq[i]*rsqrtf(vq[i]+1e-5f)))*LOG2E;
    biask[i] = bk[i] - mk[i]*(gk[i]*rsqrtf(vk[i]+1e-5f));
  }
}

// ------- preprocessing: z=0 upsample+Qconv ; z=1 x2 stage+K+V[0:128) ; z=2 x2 stage+V[128:256) -------
__global__ __launch_bounds__(256, 2)
void pre_kernel(const float* __restrict__ x1, const float* __restrict__ x2,
                const unsigned short* __restrict__ wqb,
                const unsigned short* __restrict__ wkb,
                const unsigned short* __restrict__ wvb,
                const float* __restrict__ biasq, const float* __restrict__ biask,
                const float* __restrict__ biasv,
                float* __restrict__ x1u,
                unsigned short* __restrict__ Qb, unsigned short* __restrict__ Kb,
                unsigned short* __restrict__ Vb){
  __shared__ unsigned short xt[64*260];
  int b = blockIdx.y;
  int t = threadIdx.x;
  int lane = t&63, w = t>>6, l15 = lane&15, g = lane>>4;

  if (blockIdx.z == 0){
    int y = blockIdx.x;
    float fy = 0.5f*y - 0.25f;
    float y0f = floorf(fy); float wy = fy - y0f;
    int y0 = max(0,min(31,(int)y0f)), y1 = max(0,min(31,(int)y0f+1));
    int x = t & 63, cg = t >> 6;
    float fx = 0.5f*x - 0.25f;
    float x0f = floorf(fx); float wx = fx - x0f;
    int x0 = max(0,min(31,(int)x0f)), x1i = max(0,min(31,(int)x0f+1));
    #pragma unroll 8
    for (int i=0;i<64;i++){
      int c = cg + i*4;
      const float* s0 = x1 + ((size_t)(b*C_ + c)*32 + y0)*32;
      const float* s1 = x1 + ((size_t)(b*C_ + c)*32 + y1)*32;
      float v00=s0[x0], v01=s0[x1i], v10=s1[x0], v11=s1[x1i];
      float v0 = v00 + wx*(v01-v00), v1 = v10 + wx*(v11-v10);
      float val = v0 + wy*(v1-v0);
      x1u[(size_t)(b*C_ + c)*N_ + y*64 + x] = val;
      xt[x*260 + c] = f2b(val);
    }
    __syncthreads();
    const unsigned short* arow = xt + (w*16+l15)*260 + g*8;
    short8 a[8];
    #pragma unroll
    for (int kk=0;kk<8;kk++){
      short4_ lo = *(const short4_*)(arow + kk*32);
      short4_ hi = *(const short4_*)(arow + kk*32 + 4);
      short8 af;
      af[0]=lo[0];af[1]=lo[1];af[2]=lo[2];af[3]=lo[3];
      af[4]=hi[0];af[5]=hi[1];af[6]=hi[2];af[7]=hi[3];
      a[kk]=af;
    }
    #pragma unroll
    for (int ot=0; ot<2; ot++){
      int o = ot*16 + l15;
      const unsigned short* wrow = wqb + o*C_ + g*8;
      float4v acc = {0.f,0.f,0.f,0.f};
      #pragma unroll
      for (int kk=0;kk<8;kk++){
        short8 bf = *(const short8*)(wrow + kk*32);
        acc = __builtin_amdgcn_mfma_f32_16x16x32_bf16(a[kk], bf, acc, 0,0,0);
      }
      float bs = biasq[o];
      #pragma unroll
      for (int r=0;r<4;r++){
        float yv = acc[r] + bs;
        yv = yv >= 0.f ? yv : 0.1f*yv;
        int m = y*64 + w*16 + g*4 + r;
        Qb[(size_t)(b*N_+m)*32 + o] = f2b(yv);
      }
    }
  } else {
    int n0 = blockIdx.x*64;
    int n = t & 63, cg = t >> 6;
    #pragma unroll 8
    for (int i=0;i<64;i++){
      int c = cg + i*4;
      float v = x2[(size_t)(b*C_ + c)*N_ + n0 + n];
      xt[n*260 + c] = f2b(v);
    }
    __syncthreads();
    const unsigned short* arow = xt + (w*16+l15)*260 + g*8;
    short8 a[8];
    #pragma unroll
    for (int kk=0;kk<8;kk++){
      short4_ lo = *(const short4_*)(arow + kk*32);
      short4_ hi = *(const short4_*)(arow + kk*32 + 4);
      short8 af;
      af[0]=lo[0];af[1]=lo[1];af[2]=lo[2];af[3]=lo[3];
      af[4]=hi[0];af[5]=hi[1];af[6]=hi[2];af[7]=hi[3];
      a[kk]=af;
    }
    if (blockIdx.z == 1){
      #pragma unroll
      for (int ot=0; ot<2; ot++){
        int o = ot*16 + l15;
        const unsigned short* wrow = wkb + o*C_ + g*8;
        float4v acc = {0.f,0.f,0.f,0.f};
        #pragma unroll
        for (int kk=0;kk<8;kk++){
          short8 bf = *(const short8*)(wrow + kk*32);
          acc = __builtin_amdgcn_mfma_f32_16x16x32_bf16(a[kk], bf, acc, 0,0,0);
        }
        float bs = biask[o];
        #pragma unroll
        for (int r=0;r<4;r++){
          float yv = acc[r] + bs;
          yv = yv >= 0.f ? yv : 0.1f*yv;
          int m = n0 + w*16 + g*4 + r;
          Kb[(size_t)(b*N_+m)*32 + o] = f2b(yv);
        }
      }
    }
    int obase = (blockIdx.z == 1) ? 0 : 8;
    #pragma unroll
    for (int ot=0; ot<8; ot++){
      int o = (obase + ot)*16 + l15;
      const unsigned short* wrow = wvb + (size_t)o*C_ + g*8;
      float4v acc = {0.f,0.f,0.f,0.f};
      #pragma unroll
      for (int kk=0;kk<8;kk++){
        short8 bf = *(const short8*)(wrow + kk*32);
        acc = __builtin_amdgcn_mfma_f32_16x16x32_bf16(a[kk], bf, acc, 0,0,0);
      }
      float bs = biasv[o];
      #pragma unroll
      for (int r=0;r<4;r++){
        float yv = acc[r] + bs;
        yv = yv >= 0.f ? yv : 0.1f*yv;
        int m = n0 + w*16 + g*4 + r;
        Vb[(size_t)(b*C_ + o)*N_ + m] = f2b(yv);
      }
    }
  }
}

// ---------------- fused flash attention + gamma*out + x1u ----------------
// Grid 256 (XCD-swizzled), 512 threads (8 waves), M=64/block, full-n sweep.
// cq = w&3 (c-range 64), ks = w>>2 (k-half 32). Waves 0-3 also own softmax of
// 16-row tile w (pipelined one tile ahead, P/flags/scl parity dbuf).
// V [256c][64n] staged in LDS via global_load_lds dbuf, XOR-swizzled rows.
// ONE barrier per iteration. Epilogue combines the two k-partials via LDS.
__global__ __launch_bounds__(512, 2)
void attn_kernel(const unsigned short* __restrict__ Qb,
                 const unsigned short* __restrict__ Kb,
                 const unsigned short* __restrict__ Vb,
                 const float* __restrict__ x1u,
                 const float* __restrict__ gamma_p,
                 float* __restrict__ out){
  // [0,65536): V dbuf (2x32768)  | epilogue: cbuf[4 cq][64 m][65 f32] (66560 B, overlays V+P head)
  // [65536,81920): P parity dbuf (2 x 4 tiles x 2048)
  // [81920): flags[2][4] ; [81952): scl[2][64] ; [82464): lst[64]
  __shared__ __align__(16) char smem[82720];
  int* flagsB = (int*)(smem + 81920);
  float* sclB = (float*)(smem + 81952);
  float* lst  = (float*)(smem + 82464);

  int wg = blockIdx.y*64 + blockIdx.x;
  int id = (wg & 7)*32 + (wg >> 3);           // bijective XCD swizzle (256 = 8*32)
  int b = id >> 6, mblk = id & 63;
  int t = threadIdx.x, lane = t & 63, w = t >> 6;
  int l15 = lane & 15, g = lane >> 4;
  int swz = (l15 & 7) << 4;
  int cq = w & 3, ks = w >> 2;

  short8 qf{};
  if (w < 4)
    qf = *(const short8*)(Qb + (size_t)(b*N_ + mblk*64 + w*16 + l15)*32 + g*8);

  float4v acc[4][4];   // [mt][ct] : 64 m x 64 c partial (k-half ks)
  #pragma unroll
  for (int mt=0;mt<4;mt++)
    #pragma unroll
    for (int ct=0;ct<4;ct++) acc[mt][ct] = (float4v){0.f,0.f,0.f,0.f};
  float mrow = -1e30f, lrun = 0.f;
  const float4v zero4 = {0.f,0.f,0.f,0.f};

  // staging: 2048 16B chunks over 512 threads -> 4 each (linear LDS, inv-swizzled src)
  size_t goff[4]; int loff[4];
  #pragma unroll
  for (int j=0;j<4;j++){
    int i = j*512 + t;
    int c = i >> 3, jj = i & 7;
    loff[j] = i*16;
    goff[j] = (size_t)(b*C_ + c)*(N_*2) + ((size_t)((jj ^ (c & 7)) << 4));
  }
  const char* Vbyte = (const char*)Vb;
  const short* kbase = (const short*)Kb + (size_t)(b*N_ + l15)*32 + g*8;

  auto stageV = [&](int tt, char* buf){
    const char* src = Vbyte + tt*128;
    #pragma unroll
    for (int j=0;j<4;j++) gload16(src + goff[j], buf + loff[j]);
  };
  auto loadK = [&](short8 (&kf)[4], int tt){
    const short* kp = kbase + (size_t)tt*64*32;
    #pragma unroll
    for (int j=0;j<4;j++) kf[j] = *(const short8*)(kp + j*512);
  };

  // QK(tile)+softmax -> P/flags/scl parity buffer pdst
  auto softmax_step = [&](const short8 (&kf)[4], int pdst){
    float4v s[4];
    #pragma unroll
    for (int j=0;j<4;j++)
      s[j] = __builtin_amdgcn_mfma_f32_16x16x32_bf16(kf[j], qf, zero4, 0, 0, 0);
    float tmax = fmaxf(fmaxf(fmaxf(s[0][0],s[0][1]),fmaxf(s[0][2],s[0][3])),
               fmaxf(fmaxf(fmaxf(s[1][0],s[1][1]),fmaxf(s[1][2],s[1][3])),
               fmaxf(fmaxf(fmaxf(s[2][0],s[2][1]),fmaxf(s[2][2],s[2][3])),
                     fmaxf(fmaxf(s[3][0],s[3][1]),fmaxf(s[3][2],s[3][3])))));
    int trig = __any((tmax > mrow + 8.f) ? 1 : 0) ? 1 : 0;
    if (lane == 0) flagsB[pdst*4 + w] = trig;
    if (trig){
      float tm = fmaxf(tmax, __shfl_xor(tmax, 16));
      tm = fmaxf(tm, __shfl_xor(tm, 32));
      float mnew = fmaxf(mrow, tm);
      float sc = exp2f(mrow - mnew);
      mrow = mnew; lrun *= sc;
      if (lane < 16) sclB[pdst*64 + w*16 + l15] = sc;
    }
    char* pw = smem + 65536 + pdst*8192 + w*2048 + l15*128;
    #pragma unroll
    for (int j=0;j<4;j++){
      float p0 = exp2f(s[j][0]-mrow), p1 = exp2f(s[j][1]-mrow);
      float p2 = exp2f(s[j][2]-mrow), p3 = exp2f(s[j][3]-mrow);
      lrun += (p0+p1)+(p2+p3);
      u32 lo = cvtpk(p0, p1);
      u32 hi = cvtpk(p2, p3);
      *(uint2v*)(pw + ((j*32 + g*8) ^ swz)) = (uint2v){lo, hi};
    }
  };

  auto body = [&](int tt, short8 (&kC)[4], short8 (&kN)[4]){
    int pp = tt & 1, vb = tt & 1;
    char* vbc = smem + vb*32768;
    if (tt < 63) stageV(tt+1, smem + (vb^1)*32768);
    if (w < 4){
      loadK(kN, (tt+2) & 63);          // prefetch K(t+2) (wrap harmless)
      if (tt < 63) softmax_step(kC, pp ^ 1);   // P(t+1)
    }
    // rescale partials with flags/scl of P(t)
    #pragma unroll
    for (int mt=0;mt<4;mt++){
      if (flagsB[pp*4 + mt]){
        float4v sv = *(float4v*)(sclB + pp*64 + mt*16 + g*4);
        #pragma unroll
        for (int ct=0;ct<4;ct++){
          acc[mt][ct][0]*=sv[0]; acc[mt][ct][1]*=sv[1];
          acc[mt][ct][2]*=sv[2]; acc[mt][ct][3]*=sv[3];
        }
      }
    }
    // PV(t): k-half ks, c-range cq*64
    int ko = (ks*64 + g*16) ^ swz;
    short8 pa[4], vf[4];
    #pragma unroll
    for (int mt=0;mt<4;mt++)
      pa[mt] = *(const short8*)(smem + 65536 + pp*8192 + mt*2048 + l15*128 + ko);
    #pragma unroll
    for (int ct=0;ct<4;ct++)
      vf[ct] = *(const short8*)(vbc + (cq*64 + ct*16 + l15)*128 + ko);
    __builtin_amdgcn_s_setprio(1);
    #pragma unroll
    for (int mt=0;mt<4;mt++)
      #pragma unroll
      for (int ct=0;ct<4;ct++)
        acc[mt][ct] = __builtin_amdgcn_mfma_f32_16x16x32_bf16(pa[mt], vf[ct], acc[mt][ct], 0, 0, 0);
    __builtin_amdgcn_s_setprio(0);
    __syncthreads();   // drains stage(t+1) DMA; publishes P(t+1)
  };

  // prologue: stage V(0); softmax(0) -> P buf0 ; kA = K(1)
  short8 kA[4], kB[4];
  stageV(0, smem);
  if (w < 4){
    short8 k0[4];
    loadK(k0, 0);
    softmax_step(k0, 0);
    loadK(kA, 1);
  }
  __syncthreads();

  for (int tt=0; tt<64; tt+=2){
    body(tt,   kA, kB);
    body(tt+1, kB, kA);
  }

  // ---------- epilogue: l-reduce, k-partial combine, normalize, store ----------
  if (w < 4){
    lrun += __shfl_xor(lrun, 16);
    lrun += __shfl_xor(lrun, 32);
    if (lane < 16) lst[w*16 + l15] = lrun;
  }
  float* cb = (float*)smem + cq*4160;   // [64 m][65] f32 per cq
  if (ks == 1){
    #pragma unroll
    for (int mt=0;mt<4;mt++)
      #pragma unroll
      for (int ct=0;ct<4;ct++)
        #pragma unroll
        for (int r=0;r<4;r++)
          cb[(mt*16 + g*4 + r)*65 + ct*16 + l15] = acc[mt][ct][r];
  }
  __syncthreads();
  if (ks == 0){
    float4v lv[4];
    #pragma unroll
    for (int mt=0;mt<4;mt++) lv[mt] = *(float4v*)(lst + mt*16 + g*4);
    #pragma unroll
    for (int mt=0;mt<4;mt++)
      #pragma unroll
      for (int ct=0;ct<4;ct++)
        #pragma unroll
        for (int r=0;r<4;r++){
          int idx = (mt*16 + g*4 + r)*65 + ct*16 + l15;
          cb[idx] = (acc[mt][ct][r] + cb[idx]) / lv[mt][r];
        }
  }
  __syncthreads();
  float gm = gamma_p[0];
  const float* xr = x1u + (size_t)(b*C_ + cq*64 + ks*32)*N_ + mblk*64;
  float* orow = out + (size_t)(b*C_ + cq*64 + ks*32)*N_ + mblk*64;
  #pragma unroll 8
  for (int i=0; i<32; i++){
    int c_l = ks*32 + i;
    float v = cb[lane*65 + c_l];
    orow[(size_t)i*N_ + lane] = gm*v + xr[(size_t)i*N_ + lane];
  }
}

extern "C" void kernel_launch(void* const* d_in, const int* in_sizes, int n_in,
                              void* d_out, int out_size, void* d_ws, size_t ws_size,
                              hipStream_t stream){
  (void)in_sizes; (void)n_in; (void)out_size; (void)ws_size;
  const float* x1 = (const float*)d_in[0];
  const float* x2 = (const float*)d_in[1];
  const float* wq = (const float*)d_in[2];
  const float* wk = (const float*)d_in[3];
  const float* wv = (const float*)d_in[4];
  const float* gq = (const float*)d_in[5];
  const float* bq = (const float*)d_in[6];
  const float* mq = (const float*)d_in[7];
  const float* vq = (const float*)d_in[8];
  const float* gk = (const float*)d_in[9];
  const float* bk = (const float*)d_in[10];
  const float* mk = (const float*)d_in[11];
  const float* vk = (const float*)d_in[12];
  const float* gv = (const float*)d_in[13];
  const float* bv = (const float*)d_in[14];
  const float* mv = (const float*)d_in[15];
  const float* vv = (const float*)d_in[16];
  const float* gamma = (const float*)d_in[17];
  float* out = (float*)d_out;

  char* p = (char*)d_ws;
  float* x1u          = (float*)p;          p += (size_t)B_*C_*N_*4;   // 16 MB
  unsigned short* Qb  = (unsigned short*)p; p += (size_t)B_*N_*32*2;   // 1 MB
  unsigned short* Kb  = (unsigned short*)p; p += (size_t)B_*N_*32*2;   // 1 MB
  unsigned short* Vb  = (unsigned short*)p; p += (size_t)B_*C_*N_*2;   // 8 MB
  unsigned short* wqb = (unsigned short*)p; p += 32*256*2;
  unsigned short* wkb = (unsigned short*)p; p += 32*256*2;
  unsigned short* wvb = (unsigned short*)p; p += 256*256*2;
  float* biasq        = (float*)p;          p += 32*4;
  float* biask        = (float*)p;          p += 32*4;
  float* biasv        = (float*)p;          p += 256*4;

  fold_w_kernel<<<256, 256, 0, stream>>>(wq,wk,wv,gq,bq,mq,vq,gk,bk,mk,vk,gv,bv,mv,vv,
                                         wqb,wkb,wvb,biasq,biask,biasv);
  pre_kernel<<<dim3(64,4,3), 256, 0, stream>>>(x1, x2, wqb, wkb, wvb,
                                               biasq, biask, biasv, x1u, Qb, Kb, Vb);
  attn_kernel<<<dim3(64,4), 512, 0, stream>>>(Qb, Kb, Vb, x1u, gamma, out);
}